// Round 18
// baseline (166.636 us; speedup 1.0000x reference)
//
#include <hip/hip_runtime.h>
#include <hip/hip_bf16.h>
#include <math.h>

// Problem constants (from reference)
#define BB    2
#define TT    1024
#define HID   1024
#define NQ    8
#define NK    4
#define DK    128
#define DV    128
#define TOT   3088      // 1024+512+512+1024+8+8
#define CONVD 2048
#define KSZ   4
#define BT    (BB*TT)   // 2048
#define CHUNK 64
#define NCHUNK (TT/CHUNK)   // 16
#define NBH   (BB*NQ)       // 16
#define NPAD1 3200          // 3088 padded to 25*128
#define JW    32            // phaseB column-group width

typedef __attribute__((ext_vector_type(8))) short short8v;
typedef __attribute__((ext_vector_type(4))) float f32x4;
typedef unsigned short ushort_t;
typedef unsigned int uint_t;

__device__ __forceinline__ float siluf(float x)     { return x / (1.f + expf(-x)); }
__device__ __forceinline__ float sigmoidf_(float x) { return 1.f / (1.f + expf(-x)); }
__device__ __forceinline__ float softplusf_(float x){ return x > 15.f ? x : log1pf(expf(x)); }

__device__ __forceinline__ ushort_t f2bf(float f) {
    uint_t u = __builtin_bit_cast(uint_t, f);
    u = (u + 0x7fff + ((u >> 16) & 1)) >> 16;
    return (ushort_t)u;
}
__device__ __forceinline__ float bf2f(ushort_t u) {
    uint_t v = ((uint_t)u) << 16;
    return __builtin_bit_cast(float, v);
}
__device__ __forceinline__ ushort4 pack4(f32x4 v) {
    ushort4 p; p.x = f2bf(v[0]); p.y = f2bf(v[1]); p.z = f2bf(v[2]); p.w = f2bf(v[3]);
    return p;
}

// LDS-only barrier: drain this wave's LDS ops, then s_barrier.
__device__ __forceinline__ void lds_barrier() {
    asm volatile("s_waitcnt lgkmcnt(0)" ::: "memory");
    __builtin_amdgcn_s_barrier();
}

// ---------------- fused prep: f2bf(x) + transpose/convert of w_in, w_out ----------------
__device__ __forceinline__ void transpose_body(const float* __restrict__ src,
                                               ushort_t* __restrict__ dst,
                                               int K, int N, int bx, int by) {
    __shared__ float tile[32][33];
    int n0 = bx * 32, k0 = by * 32;
    int c = threadIdx.x & 31, rbase = threadIdx.x >> 5;
    #pragma unroll
    for (int i = 0; i < 4; i++) {
        int r = rbase + i * 8;
        int n = n0 + c;
        tile[r][c] = (n < N) ? src[(size_t)(k0 + r) * N + n] : 0.f;
    }
    __syncthreads();
    #pragma unroll
    for (int i = 0; i < 4; i++) {
        int r = rbase + i * 8;
        dst[(size_t)(n0 + r) * K + k0 + c] = f2bf(tile[c][r]);
    }
}

__global__ __launch_bounds__(256) void prep_kernel(const float* __restrict__ x,
                                                   const float* __restrict__ w_in,
                                                   const float* __restrict__ w_out,
                                                   ushort_t* __restrict__ xb,
                                                   ushort_t* __restrict__ bt1,
                                                   ushort_t* __restrict__ bt2) {
    int bid = blockIdx.x;
    if (bid < 2048) {                               // x -> bf16 (2M elems)
        int i = (bid * 256 + threadIdx.x) * 4;
        float4 v = *(const float4*)(x + i);
        ushort4 o;
        o.x = f2bf(v.x); o.y = f2bf(v.y); o.z = f2bf(v.z); o.w = f2bf(v.w);
        *(ushort4*)(xb + i) = o;
    } else if (bid < 2048 + 3200) {                 // w_in^T: 100 x 32 tiles
        int t = bid - 2048;
        transpose_body(w_in, bt1, HID, TOT, t % 100, t / 100);
    } else {                                        // w_out^T: 32 x 32 tiles
        int t = bid - 5248;
        transpose_body(w_out, bt2, HID, HID, t % 32, t / 32);
    }
}

// ---------------- bf16 MFMA GEMM: C[M,N] = A[M,K] @ BT[N,K]^T ----------------
template <bool BF16OUT>
__global__ __launch_bounds__(256) void gemm_bf16(const ushort_t* __restrict__ A,
                                                 const ushort_t* __restrict__ BTm,
                                                 void* __restrict__ Cv,
                                                 int K, int Nc, int ldc, int nx) {
    __shared__ __align__(16) ushort_t As[128 * 64];   // 16KB
    __shared__ __align__(16) ushort_t Bs[128 * 64];   // 16KB
    int tid = threadIdx.x;
    int wave = tid >> 6, lane = tid & 63;
    int wr = wave >> 1, wc = wave & 1;
    int lr = lane & 15, lg = lane >> 4;

    int flat = blockIdx.x;
    int swz = (flat & 7) * ((int)gridDim.x >> 3) + (flat >> 3);   // nwg % 8 == 0
    int col0 = (swz % nx) * 128, row0 = (swz / nx) * 128;

    f32x4 acc[4][4];
    #pragma unroll
    for (int m = 0; m < 4; m++)
        #pragma unroll
        for (int n = 0; n < 4; n++) acc[m][n] = (f32x4){0.f, 0.f, 0.f, 0.f};

    int srowA = (lane >> 3);
    int skoff = ((lane & 7) ^ (lane >> 3)) * 8;

    for (int k0 = 0; k0 < K; k0 += 64) {
        #pragma unroll
        for (int j = 0; j < 4; j++) {
            int i = wave * 4 + j;
            int r = 8 * i + srowA;
            __builtin_amdgcn_global_load_lds(
                (const __attribute__((address_space(1))) void*)(A + (size_t)(row0 + r) * K + k0 + skoff),
                (__attribute__((address_space(3))) void*)(As + i * 512), 16, 0, 0);
            __builtin_amdgcn_global_load_lds(
                (const __attribute__((address_space(1))) void*)(BTm + (size_t)(col0 + r) * K + k0 + skoff),
                (__attribute__((address_space(3))) void*)(Bs + i * 512), 16, 0, 0);
        }
        __syncthreads();

        #pragma unroll
        for (int kk = 0; kk < 2; kk++) {
            short8v af[4], bf[4];
            #pragma unroll
            for (int m = 0; m < 4; m++) {
                int row = wr * 64 + m * 16 + lr;
                int pb = (row * 128 + kk * 64 + lg * 16) ^ ((row & 7) << 4);
                af[m] = *(const short8v*)((const char*)As + pb);
            }
            #pragma unroll
            for (int n = 0; n < 4; n++) {
                int row = wc * 64 + n * 16 + lr;
                int pb = (row * 128 + kk * 64 + lg * 16) ^ ((row & 7) << 4);
                bf[n] = *(const short8v*)((const char*)Bs + pb);
            }
            #pragma unroll
            for (int m = 0; m < 4; m++)
                #pragma unroll
                for (int n = 0; n < 4; n++)
                    acc[m][n] = __builtin_amdgcn_mfma_f32_16x16x32_bf16(af[m], bf[n], acc[m][n], 0, 0, 0);
        }
        __syncthreads();
    }

    #pragma unroll
    for (int m = 0; m < 4; m++) {
        #pragma unroll
        for (int n = 0; n < 4; n++) {
            int row = row0 + wr * 64 + m * 16 + lg * 4;
            int col = col0 + wc * 64 + n * 16 + lr;
            if (col < Nc) {
                if (BF16OUT) {
                    ushort_t* C = (ushort_t*)Cv;
                    #pragma unroll
                    for (int e = 0; e < 4; e++)
                        C[(size_t)(row + e) * ldc + col] = f2bf(acc[m][n][e]);
                } else {
                    float* C = (float*)Cv;
                    #pragma unroll
                    for (int e = 0; e < 4; e++)
                        C[(size_t)(row + e) * ldc + col] = acc[m][n][e];
                }
            }
        }
    }
}

// ---------------- conv + silu + split + l2norm + beta/g (bf16 mixed input) ----------------
__global__ __launch_bounds__(256) void conv_split_kernel(const ushort_t* __restrict__ mixedb,
                                                         const float* __restrict__ conv_w,
                                                         const float* __restrict__ A_log,
                                                         const float* __restrict__ dt_bias,
                                                         ushort_t* __restrict__ qb,
                                                         ushort_t* __restrict__ kb,
                                                         float* __restrict__ kn,
                                                         float* __restrict__ vn,
                                                         float* __restrict__ beta,
                                                         float* __restrict__ g) {
    int raw = blockIdx.x;
    int bt = ((raw & 7) << 8) | (raw >> 3);
    int t = bt & (TT - 1);
    int tid = threadIdx.x;
    int c0 = tid * 8;

    float val[8];
    #pragma unroll
    for (int i = 0; i < 8; i++) val[i] = 0.f;
    #pragma unroll
    for (int j = 0; j < KSZ; j++) {
        int tt = t - (KSZ - 1) + j;
        if (tt >= 0) {
            short8v v = *(const short8v*)(mixedb + (size_t)(bt - (KSZ - 1) + j) * TOT + c0);
            #pragma unroll
            for (int i = 0; i < 8; i++) val[i] += bf2f((ushort_t)v[i]) * conv_w[(c0 + i) * KSZ + j];
        }
    }
    #pragma unroll
    for (int i = 0; i < 8; i++) val[i] = siluf(val[i]);

    float ss = 0.f;
    #pragma unroll
    for (int i = 0; i < 8; i++) ss += val[i] * val[i];
    #pragma unroll
    for (int m = 1; m < 16; m <<= 1) ss += __shfl_xor(ss, m, 64);
    float rs = rsqrtf(ss + 1e-6f);

    if (tid < 128) {                      // q -> l2norm * DK^-0.5, bf16 only
        float sc = rs * 0.08838834764831845f;
        short8v pk;
        #pragma unroll
        for (int i = 0; i < 8; i++) pk[i] = (short)f2bf(val[i] * sc);
        *(short8v*)(qb + (size_t)bt * 1024 + c0) = pk;
    } else if (tid < 192) {               // k -> l2norm, f32 + bf16
        int o = c0 - 1024;
        short8v pk;
        #pragma unroll
        for (int i = 0; i < 8; i++) {
            float kv = val[i] * rs;
            kn[(size_t)bt * 512 + o + i] = kv;
            pk[i] = (short)f2bf(kv);
        }
        *(short8v*)(kb + (size_t)bt * 512 + o) = pk;
    } else {                              // v -> silu only, f32
        #pragma unroll
        for (int i = 0; i < 8; i++) vn[(size_t)bt * 512 + (c0 - 1536) + i] = val[i];
    }
    if (tid < 8) {
        beta[bt * 8 + tid] = sigmoidf_(bf2f(mixedb[(size_t)bt * TOT + 3072 + tid]));
    } else if (tid < 16) {
        int h = tid - 8;
        g[bt * 8 + h] = -expf(A_log[h]) *
                        softplusf_(bf2f(mixedb[(size_t)bt * TOT + 3080 + h]) + dt_bias[h]);
    }
}

// ---------------- Phase A: per-chunk UT transform (MFMA M, register substitution) ----------------
__global__ __launch_bounds__(256) void phaseA_kernel(const float* __restrict__ kn,
                                                     const float* __restrict__ vn,
                                                     const float* __restrict__ beta,
                                                     const float* __restrict__ g,
                                                     ushort_t* __restrict__ Wb,
                                                     ushort_t* __restrict__ Znegb,
                                                     ushort_t* __restrict__ knT,
                                                     float* __restrict__ Bvec) {
    int bh = blockIdx.x & 15, c = blockIdx.x >> 4;
    int chunk = bh * 16 + c;
    int b = bh >> 3, h = bh & 7, hk = h >> 1;
    int bt0 = b * TT + c * CHUNK;
    int tid = threadIdx.x;
    int wave = tid >> 6, lane = tid & 63;
    int lr = lane & 15, lg = lane >> 4;

    __shared__ __align__(16) ushort_t kcb[64 * 128];  // bf16 k, XOR-swizzled rows
    __shared__ float Ms[64][65];
    __shared__ float Bv[64], Bev[64], bev[64];

    if (tid < 64) {   // wave 0: cumulative log-decay scan
        float v = g[(size_t)(bt0 + tid) * 8 + h];
        #pragma unroll
        for (int off = 1; off < 64; off <<= 1) {
            float n = __shfl_up(v, off, 64);
            if (tid >= off) v += n;
        }
        Bv[tid] = v;
        Bev[tid] = expf(v);
        bev[tid] = beta[(size_t)(bt0 + tid) * 8 + h];
        Bvec[chunk * 64 + tid] = v;
    }
    // stage k as bf16, swizzled: byte (r*256 + k*2) ^ ((r&7)<<4)
    for (int i = tid; i < 1024; i += 256) {
        int r = i >> 4, k16 = i & 15;
        const float* src = kn + (size_t)(bt0 + r) * 512 + hk * 128 + k16 * 8;
        float4 v0 = *(const float4*)src;
        float4 v1 = *(const float4*)(src + 4);
        short8v pk;
        pk[0] = (short)f2bf(v0.x); pk[1] = (short)f2bf(v0.y);
        pk[2] = (short)f2bf(v0.z); pk[3] = (short)f2bf(v0.w);
        pk[4] = (short)f2bf(v1.x); pk[5] = (short)f2bf(v1.y);
        pk[6] = (short)f2bf(v1.z); pk[7] = (short)f2bf(v1.w);
        int a = (r * 256 + k16 * 16) ^ ((r & 7) << 4);
        *(short8v*)((char*)kcb + a) = pk;
    }
    __syncthreads();

    // M via MFMA: wave w -> rows [16w,16w+16), s-bands 0..w
    {
        int t_lane = wave * 16 + lr;
        short8v af[4];
        #pragma unroll
        for (int ks = 0; ks < 4; ks++) {
            int a = (t_lane * 256 + ks * 64 + lg * 16) ^ ((t_lane & 7) << 4);
            af[ks] = *(const short8v*)((const char*)kcb + a);
        }
        for (int sb = 0; sb <= wave; sb++) {
            f32x4 macc = {0.f, 0.f, 0.f, 0.f};
            int s_lane = sb * 16 + lr;
            #pragma unroll
            for (int ks = 0; ks < 4; ks++) {
                int a = (s_lane * 256 + ks * 64 + lg * 16) ^ ((s_lane & 7) << 4);
                short8v bfr = *(const short8v*)((const char*)kcb + a);
                macc = __builtin_amdgcn_mfma_f32_16x16x32_bf16(af[ks], bfr, macc, 0, 0, 0);
            }
            #pragma unroll
            for (int e = 0; e < 4; e++) {
                int trow = wave * 16 + lg * 4 + e;
                int scol = sb * 16 + lr;
                Ms[trow][scol] = (scol < trow) ? macc[e] * bev[trow] * expf(Bv[trow] - Bv[scol]) : 0.f;
            }
        }
    }

    // X init in registers: col tid<128 -> beta*v ; col tid>=128 -> beta*Gamma*k
    float Xr[64];
    if (tid < 128) {
        #pragma unroll
        for (int t = 0; t < 64; t++)
            Xr[t] = bev[t] * vn[(size_t)(bt0 + t) * 512 + hk * 128 + tid];
    } else {
        int r = tid - 128;
        #pragma unroll
        for (int t = 0; t < 64; t++)
            Xr[t] = bev[t] * Bev[t] * kn[(size_t)(bt0 + t) * 512 + hk * 128 + r];
    }
    __syncthreads();   // Ms ready

    // forward substitution, column-private, zero barriers, static indexing
    #pragma unroll
    for (int t = 1; t < 64; t++) {
        float a0 = 0.f, a1 = 0.f, a2 = 0.f, a3 = 0.f;
        #pragma unroll
        for (int s = 0; s + 4 <= t; s += 4) {
            a0 += Ms[t][s] * Xr[s];     a1 += Ms[t][s + 1] * Xr[s + 1];
            a2 += Ms[t][s + 2] * Xr[s + 2]; a3 += Ms[t][s + 3] * Xr[s + 3];
        }
        #pragma unroll
        for (int s = t & ~3; s < t; s++) a0 += Ms[t][s] * Xr[s];
        Xr[t] -= (a0 + a1) + (a2 + a3);
    }

    if (tid < 128) {
        ushort_t* Wc = Wb + (size_t)chunk * 8192 + tid;
        #pragma unroll
        for (int t = 0; t < 64; t++) Wc[t * 128] = f2bf(Xr[t]);
    } else {
        ushort_t* Zc = Znegb + (size_t)chunk * 8192 + (tid - 128);
        #pragma unroll
        for (int t = 0; t < 64; t++) Zc[t * 128] = f2bf(-Xr[t]);
    }

    // transposed bf16 k, PER-BH copy (XCD-local for phaseB)
    {
        ushort_t* kT = knT + (size_t)bh * 131072 + c * 64;
        for (int i = tid; i < 8192; i += 256) {
            int r = i >> 6, tt = i & 63;
            int a = (tt * 256 + r * 2) ^ ((tt & 7) << 4);
            kT[(size_t)r * 1024 + tt] = *(const ushort_t*)((const char*)kcb + a);
        }
    }
}

// ---------------- Phase B (MFMA, 4 waves, loads-BEFORE-stores prefetch) ----------------
// KEY (r18): global stores increment vmcnt and retire IN ORDER, so any wait on a load
// issued AFTER a store transitively waits for the store to retire to HBM. Every prior
// variant issued SgT/UTc stores before the next-chunk prefetch -> ~2 store-retire
// latencies on the critical path per chunk. Fix: issue the ENTIRE next-chunk prefetch
// cluster at the TOP of each iteration, before any stores (x2 unroll, static A/B sets).
__device__ __forceinline__ int swzSt(int j, int k) {   // St[j][k] bf16
    int a = j * 256 + k * 2;
    return a ^ ((j & 7) << 4);
}
__device__ __forceinline__ int swzUt(int j, int s) {   // Ut[j][s] bf16
    int a = j * 128 + s * 2;
    return a ^ ((j & 7) << 4);
}

__device__ __forceinline__ void phaseB_prefetch(int chunk, int cloc,
                                                const ushort_t* kTbase,
                                                const ushort_t* Znegb,
                                                const ushort_t* Wb,
                                                const float* Bvec,
                                                int j0, int lane, int wave,
                                                short8v (&za)[4], short8v (&ka)[4],
                                                ushort_t (&wvr)[8], f32x4 (&bvv)[4], float& b63) {
    int lr = lane & 15, lg = lane >> 4;
    int t0 = wave * 16;
    const ushort_t* Zc = Znegb + (size_t)chunk * 8192;
    #pragma unroll
    for (int ks = 0; ks < 4; ks++)
        za[ks] = *(const short8v*)(Zc + (size_t)(t0 + lr) * 128 + ks * 32 + lg * 8);
    const ushort_t* Wc = Wb + (size_t)chunk * 8192 + j0;
    #pragma unroll
    for (int fc = 0; fc < 2; fc++)
        #pragma unroll
        for (int e = 0; e < 4; e++)
            wvr[fc * 4 + e] = Wc[(size_t)(t0 + lg * 4 + e) * 128 + fc * 16 + lr];
    #pragma unroll
    for (int fr = 0; fr < 2; fr++)
        #pragma unroll
        for (int ss = 0; ss < 2; ss++)
            ka[fr * 2 + ss] = *(const short8v*)(kTbase +
                (size_t)(wave * 32 + fr * 16 + lr) * 1024 + cloc * 64 + ss * 32 + lg * 8);
    #pragma unroll
    for (int q = 0; q < 4; q++)
        bvv[q] = *(const f32x4*)(Bvec + chunk * 64 + (q >> 1) * 32 + lg * 8 + (q & 1) * 4);
    b63 = Bvec[chunk * 64 + 63];
}

__device__ __forceinline__ void phaseB_body(int chunk,
                                            ushort_t* SallT, ushort_t* UTg,
                                            int j0, int lane, int wave,
                                            ushort_t* St, ushort_t* Ut,
                                            f32x4 (&Sacc)[2][2],
                                            short8v (&za)[4], short8v (&ka)[4],
                                            ushort_t (&wvr)[8], f32x4 (&bvv)[4], float b63) {
    int lr = lane & 15, lg = lane >> 4;
    int t0 = wave * 16;

    // stores of S_c (chunk-start state) — AFTER this iteration's prefetch was issued
    ushort_t* SgT = SallT + (size_t)chunk * 16384;
    #pragma unroll
    for (int fr = 0; fr < 2; fr++)
        #pragma unroll
        for (int fc = 0; fc < 2; fc++) {
            int r0 = wave * 32 + fr * 16 + lg * 4;
            int j = j0 + fc * 16 + lr;
            *(ushort4*)(SgT + (size_t)j * 128 + r0) = pack4(Sacc[fr][fc]);
        }
    // C-input of product 1 from prefetched (raw bf16) W
    f32x4 Uacc[2];
    #pragma unroll
    for (int fc = 0; fc < 2; fc++)
        #pragma unroll
        for (int e = 0; e < 4; e++)
            Uacc[fc][e] = bf2f(wvr[fc * 4 + e]);

    lds_barrier();   // B1: St (prev chunk) visible

    // ---- product 1: U = W + (-Z) * S
    #pragma unroll
    for (int ks = 0; ks < 4; ks++)
        #pragma unroll
        for (int fc = 0; fc < 2; fc++) {
            short8v sb = *(const short8v*)((const char*)St + swzSt(fc * 16 + lr, ks * 32 + lg * 8));
            Uacc[fc] = __builtin_amdgcn_mfma_f32_16x16x32_bf16(za[ks], sb, Uacc[fc], 0, 0, 0);
        }
    // write U: global bf16 transposed [j][t] + LDS transposed bf16
    ushort_t* UTc = UTg + (size_t)chunk * 8192;
    #pragma unroll
    for (int fc = 0; fc < 2; fc++) {
        int jl = fc * 16 + lr;
        ushort4 pu = pack4(Uacc[fc]);
        *(ushort4*)(UTc + (size_t)(j0 + jl) * 64 + t0 + lg * 4) = pu;
        *(ushort4*)((char*)Ut + swzUt(jl, t0 + lg * 4)) = pu;
    }
    // gamma-scale state
    float gC = expf(b63);
    #pragma unroll
    for (int fr = 0; fr < 2; fr++)
        #pragma unroll
        for (int fc = 0; fc < 2; fc++)
            #pragma unroll
            for (int e = 0; e < 4; e++) Sacc[fr][fc][e] *= gC;

    lds_barrier();   // B2: Ut ready

    // per-lane decay factors from prefetched Bvec
    float eb[2][8];
    #pragma unroll
    for (int ss = 0; ss < 2; ss++)
        #pragma unroll
        for (int e = 0; e < 8; e++)
            eb[ss][e] = expf(b63 - bvv[ss * 2 + (e >> 2)][e & 3]);

    // ---- product 2: S += K_hat^T * U
    #pragma unroll
    for (int fr = 0; fr < 2; fr++) {
        #pragma unroll
        for (int ss = 0; ss < 2; ss++) {
            short8v a;
            #pragma unroll
            for (int e = 0; e < 8; e++)
                a[e] = (short)f2bf(bf2f((ushort_t)ka[fr * 2 + ss][e]) * eb[ss][e]);
            #pragma unroll
            for (int fc = 0; fc < 2; fc++) {
                short8v ub = *(const short8v*)((const char*)Ut + swzUt(fc * 16 + lr, ss * 32 + lg * 8));
                Sacc[fr][fc] = __builtin_amdgcn_mfma_f32_16x16x32_bf16(a, ub, Sacc[fr][fc], 0, 0, 0);
            }
        }
    }
    // write S^T bf16 for next chunk's product 1
    #pragma unroll
    for (int fr = 0; fr < 2; fr++)
        #pragma unroll
        for (int fc = 0; fc < 2; fc++) {
            int r = wave * 32 + fr * 16 + lg * 4;
            int j = fc * 16 + lr;
            *(ushort4*)((char*)St + swzSt(j, r)) = pack4(Sacc[fr][fc]);
        }
}

__global__ __launch_bounds__(256) void phaseB_mfma(const ushort_t* __restrict__ knT,
                                                   const ushort_t* __restrict__ Znegb,
                                                   const ushort_t* __restrict__ Wb,
                                                   const float* __restrict__ Bvec,
                                                   ushort_t* __restrict__ SallT,
                                                   ushort_t* __restrict__ UTg) {
    int bh = blockIdx.x & 15, cg = blockIdx.x >> 4;
    int j0 = cg * JW;
    int tid = threadIdx.x;
    int wave = tid >> 6, lane = tid & 63;

    __shared__ __align__(16) ushort_t St[JW * 128];
    __shared__ __align__(16) ushort_t Ut[JW * 64];

    for (int i = tid * 8; i < JW * 128; i += 2048)
        *(int4*)(St + i) = make_int4(0, 0, 0, 0);

    f32x4 Sacc[2][2];
    #pragma unroll
    for (int fr = 0; fr < 2; fr++)
        #pragma unroll
        for (int fc = 0; fc < 2; fc++) Sacc[fr][fc] = (f32x4){0.f, 0.f, 0.f, 0.f};

    const ushort_t* kTbase = knT + (size_t)bh * 131072;
    int chunk0 = bh * 16;

    // Two static register sets (A/B); prologue fills A with chunk 0.
    short8v zaA[4], kaA[4], zaB[4], kaB[4];
    ushort_t wvrA[8], wvrB[8];
    f32x4 bvvA[4], bvvB[4];
    float b63A, b63B;

    phaseB_prefetch(chunk0, 0, kTbase, Znegb, Wb, Bvec, j0, lane, wave,
                    zaA, kaA, wvrA, bvvA, b63A);

    #pragma unroll 1
    for (int c = 0; c < NCHUNK; c += 2) {
        // iteration c: FIRST issue prefetch for c+1 into set B (loads precede ALL stores
        // of this iteration in vmcnt order), then consume set A.
        phaseB_prefetch(chunk0 + c + 1, c + 1, kTbase, Znegb, Wb, Bvec, j0, lane, wave,
                        zaB, kaB, wvrB, bvvB, b63B);
        __builtin_amdgcn_sched_barrier(0);
        phaseB_body(chunk0 + c, SallT, UTg, j0, lane, wave, St, Ut, Sacc,
                    zaA, kaA, wvrA, bvvA, b63A);

        // iteration c+1: prefetch c+2 into set A (if any), consume set B.
        if (c + 2 < NCHUNK) {
            phaseB_prefetch(chunk0 + c + 2, c + 2, kTbase, Znegb, Wb, Bvec, j0, lane, wave,
                            zaA, kaA, wvrA, bvvA, b63A);
            __builtin_amdgcn_sched_barrier(0);
        }
        phaseB_body(chunk0 + c + 1, SallT, UTg, j0, lane, wave, St, Ut, Sacc,
                    zaB, kaB, wvrB, bvvB, b63B);
    }
}

// ---------------- Phase C (MFMA) + fused gated RMS norm + silu(z) -> bf16 ----------------
__global__ __launch_bounds__(256) void phaseC_mfma(const ushort_t* __restrict__ qb,
                                                   const ushort_t* __restrict__ kb,
                                                   const ushort_t* __restrict__ UTg,
                                                   const ushort_t* __restrict__ SallT,
                                                   const float* __restrict__ Bvec,
                                                   const ushort_t* __restrict__ mixedb,
                                                   const float* __restrict__ norm_w,
                                                   ushort_t* __restrict__ ginb) {
    int bh = blockIdx.x & 15, c = blockIdx.x >> 4;
    int chunk = bh * 16 + c;
    int b = bh >> 3, h = bh & 7, hk = h >> 1;
    int bt0 = b * TT + c * CHUNK;
    int tid = threadIdx.x, wave = tid >> 6, lane = tid & 63;
    int lr = lane & 15, lg = lane >> 4;

    __shared__ float Bv[64], Bev[64];
    __shared__ __align__(16) ushort_t Pb[64 * 64];   // P~ bf16, swizzled

    if (tid < 64) { float v = Bvec[chunk * 64 + tid]; Bv[tid] = v; Bev[tid] = expf(v); }
    __syncthreads();

    int t_lane = wave * 16 + lr;
    const ushort_t* qrow = qb + (size_t)(bt0 + t_lane) * 1024 + h * 128;
    short8v qa[4];
    #pragma unroll
    for (int ks = 0; ks < 4; ks++) qa[ks] = *(const short8v*)(qrow + ks * 32 + lg * 8);

    // ---- P = mask(exp(Bt-Bs) * Q K^T): wave w -> rows [16w,16w+16), all 4 s-bands
    #pragma unroll
    for (int sb = 0; sb < 4; sb++) {
        f32x4 pacc = {0.f, 0.f, 0.f, 0.f};
        const ushort_t* krow = kb + (size_t)(bt0 + sb * 16 + lr) * 512 + hk * 128;
        #pragma unroll
        for (int ks = 0; ks < 4; ks++) {
            short8v kf = *(const short8v*)(krow + ks * 32 + lg * 8);
            pacc = __builtin_amdgcn_mfma_f32_16x16x32_bf16(qa[ks], kf, pacc, 0, 0, 0);
        }
        int scol = sb * 16 + lr;
        #pragma unroll
        for (int e = 0; e < 4; e++) {
            int trow = wave * 16 + lg * 4 + e;
            float val = (scol <= trow) ? pacc[e] * expf(Bv[trow] - Bv[scol]) : 0.f;
            int a = (trow * 128 + scol * 2) ^ ((trow & 7) << 4);
            *(ushort_t*)((char*)Pb + a) = f2bf(val);
        }
    }

    // ---- QS: acc[n] = Q @ S (B-frags straight from global SallT), then scale by Gamma
    float Ge[4];
    #pragma unroll
    for (int e = 0; e < 4; e++) Ge[e] = Bev[wave * 16 + lg * 4 + e];
    const ushort_t* ST = SallT + (size_t)chunk * 16384;
    f32x4 acc[8];
    #pragma unroll
    for (int n = 0; n < 8; n++) {
        acc[n] = (f32x4){0.f, 0.f, 0.f, 0.f};
        int j = n * 16 + lr;
        #pragma unroll
        for (int rs = 0; rs < 4; rs++) {
            short8v sf = *(const short8v*)(ST + (size_t)j * 128 + rs * 32 + lg * 8);
            acc[n] = __builtin_amdgcn_mfma_f32_16x16x32_bf16(qa[rs], sf, acc[n], 0, 0, 0);
        }
        #pragma unroll
        for (int e = 0; e < 4; e++) acc[n][e] *= Ge[e];
    }
    __syncthreads();   // Pb ready

    // ---- acc += P~ @ U (A-frags from Pb LDS, B-frags from global UT)
    short8v pa[2];
    #pragma unroll
    for (int ks = 0; ks < 2; ks++) {
        int a = (t_lane * 128 + (ks * 32 + lg * 8) * 2) ^ ((t_lane & 7) << 4);
        pa[ks] = *(const short8v*)((const char*)Pb + a);
    }
    const ushort_t* UTc = UTg + (size_t)chunk * 8192;
    #pragma unroll
    for (int n = 0; n < 8; n++) {
        int j = n * 16 + lr;
        #pragma unroll
        for (int ks = 0; ks < 2; ks++) {
            short8v uf = *(const short8v*)(UTc + (size_t)j * 64 + ks * 32 + lg * 8);
            acc[n] = __builtin_amdgcn_mfma_f32_16x16x32_bf16(pa[ks], uf, acc[n], 0, 0, 0);
        }
    }

    // ---- fused gated RMS norm: row t = wave*16+lg*4+e owned by the 16 lr-lanes of this lg
    float rr[4];
    #pragma unroll
    for (int e = 0; e < 4; e++) {
        float s = 0.f;
        #pragma unroll
        for (int n = 0; n < 8; n++) s += acc[n][e] * acc[n][e];
        #pragma unroll
        for (int m = 1; m < 16; m <<= 1) s += __shfl_xor(s, m, 64);
        rr[e] = rsqrtf(s * (1.f / 128.f) + 1e-5f);
    }
    #pragma unroll
    for (int n = 0; n < 8; n++) {
        int j = n * 16 + lr;
        float nw = norm_w[j];
        #pragma unroll
        for (int e = 0; e < 4; e++) {
            int t = wave * 16 + lg * 4 + e;
            float z = bf2f(mixedb[(size_t)(bt0 + t) * TOT + 2048 + h * 128 + j]);
            ginb[(size_t)(bt0 + t) * 1024 + h * 128 + j] =
                f2bf(acc[n][e] * rr[e] * nw * siluf(z));
        }
    }
}

extern "C" void kernel_launch(void* const* d_in, const int* in_sizes, int n_in,
                              void* d_out, int out_size, void* d_ws, size_t ws_size,
                              hipStream_t stream) {
    const float* x       = (const float*)d_in[0];
    const float* w_in    = (const float*)d_in[1];
    const float* conv_w  = (const float*)d_in[2];
    const float* A_log   = (const float*)d_in[3];
    const float* dt_bias = (const float*)d_in[4];
    const float* norm_w  = (const float*)d_in[5];
    const float* w_out   = (const float*)d_in[6];
    float* out = (float*)d_out;

    // Workspace map (units: FLOATS; bf16 buffers take elem_count/2 floats!)
    float* ws = (float*)d_ws;
    float* mixedf = ws;                             // 3,162,112 f   mixed bf16 [2048][3088]
    float* kn    = mixedf + 3162112;                // 1,048,576 f   [2048][512] f32
    float* vn    = kn + (size_t)BT * 512;           // 1,048,576 f   [2048][512] f32
    float* beta  = vn + (size_t)BT * 512;           // 16,384 f
    float* gdec  = beta + BT * 8;                   // 16,384 f
    float* Wu    = gdec + BT * 8;                   // 1,048,576 f   Wb bf16 256*8192 us
    float* Bvec  = Wu + 1048576;                    // 16,384 f
    float* qbf   = Bvec + NBH * NCHUNK * 64;        // 1,048,576 f   qb: 2048*1024 bf16
    float* kbf   = qbf + 1048576;                   // 524,288 f     kb: 2048*512 bf16
    float* knTf  = kbf + 524288;                    // 1,048,576 f   knT: 16*131072 us (per-bh) ┐
    float* Znf   = knTf + 1048576;                  // 1,048,576 f   Zneg: 256*8192 us          ┘ bt1 spans these
    float* UTf   = Znf + 1048576;                   // 1,048,576 f   UT: 256*8192 us
    float* SallTf= UTf + 1048576;                   // 2,097,152 f   SallT: 256*16384 us; xb alias
    float* bt2f  = SallTf + 2097152;                // 524,288 f     w_out^T: 1024*1024 us
    // total: 14,221,312 f = 56.9 MB

    ushort_t* mixedb = (ushort_t*)mixedf;
    ushort_t* qb    = (ushort_t*)qbf;
    ushort_t* kb    = (ushort_t*)kbf;
    ushort_t* knTb  = (ushort_t*)knTf;
    ushort_t* Znegb = (ushort_t*)Znf;
    ushort_t* UTb   = (ushort_t*)UTf;
    ushort_t* SallT = (ushort_t*)SallTf;
    ushort_t* bt2   = (ushort_t*)bt2f;
    ushort_t* Wbb   = (ushort_t*)Wu;
    // liveness-disjoint aliases:
    ushort_t* xb    = (ushort_t*)SallTf;            // x bf16: dead before phaseB writes SallT
    ushort_t* bt1   = (ushort_t*)knTf;              // w_in^T bf16: fits in knTf+Znf; dead before phaseA
    ushort_t* ginb  = (ushort_t*)qbf;               // GEMM2 input: qb dead after phaseC reads it

    // 0) fused converts (f2bf + both weight transposes)
    prep_kernel<<<6272, 256, 0, stream>>>(x, w_in, w_out, xb, bt1, bt2);

    // 1) mixed(bf16) = x @ w_in  (BK=64, XCD-chunked; grid 25x16 = 400)
    gemm_bf16<true><<<400, 256, 0, stream>>>(xb, bt1, mixedb, HID, TOT, TOT, NPAD1 / 128);

    // 2) conv + silu + split + l2norm + beta/g (bf16 mixed, XCD-contiguous t remap)
    conv_split_kernel<<<BT, 256, 0, stream>>>(mixedb, conv_w, A_log, dt_bias, qb, kb, kn, vn, beta, gdec);

    // 3) chunkwise delta-rule scan (bh = bid&15 -> per-bh XCD affinity)
    phaseA_kernel<<<NBH * NCHUNK, 256, 0, stream>>>(kn, vn, beta, gdec, Wbb, Znegb, knTb, Bvec);
    phaseB_mfma<<<NBH * 4, 256, 0, stream>>>(knTb, Znegb, Wbb, Bvec, SallT, UTb);
    // 4) phaseC + fused gated RMS norm + silu(z) -> bf16 gin
    phaseC_mfma<<<NBH * NCHUNK, 256, 0, stream>>>(qb, kb, UTb, SallT, Bvec, mixedb, norm_w, ginb);

    // 5) out = gin @ w_out  (fp32 out, BK=64, XCD-chunked; grid 8x16 = 128)
    gemm_bf16<false><<<128, 256, 0, stream>>>(ginb, bt2, out, HID, HID, HID, HID / 128);
}

// Round 19
// 163.062 us; speedup vs baseline: 1.0219x; 1.0219x over previous
//
#include <hip/hip_runtime.h>
#include <hip/hip_bf16.h>
#include <math.h>

// Problem constants (from reference)
#define BB    2
#define TT    1024
#define HID   1024
#define NQ    8
#define NK    4
#define DK    128
#define DV    128
#define TOT   3088      // 1024+512+512+1024+8+8
#define CONVD 2048
#define KSZ   4
#define BT    (BB*TT)   // 2048
#define CHUNK 64
#define NCHUNK (TT/CHUNK)   // 16
#define NBH   (BB*NQ)       // 16
#define NPAD1 3200          // 3088 padded to 25*128
#define JW    32            // phaseB column-group width

typedef __attribute__((ext_vector_type(8))) short short8v;
typedef __attribute__((ext_vector_type(4))) float f32x4;
typedef unsigned short ushort_t;
typedef unsigned int uint_t;

__device__ __forceinline__ float siluf(float x)     { return x / (1.f + expf(-x)); }
__device__ __forceinline__ float sigmoidf_(float x) { return 1.f / (1.f + expf(-x)); }
__device__ __forceinline__ float softplusf_(float x){ return x > 15.f ? x : log1pf(expf(x)); }

__device__ __forceinline__ ushort_t f2bf(float f) {
    uint_t u = __builtin_bit_cast(uint_t, f);
    u = (u + 0x7fff + ((u >> 16) & 1)) >> 16;
    return (ushort_t)u;
}
__device__ __forceinline__ float bf2f(ushort_t u) {
    uint_t v = ((uint_t)u) << 16;
    return __builtin_bit_cast(float, v);
}
__device__ __forceinline__ ushort4 pack4(f32x4 v) {
    ushort4 p; p.x = f2bf(v[0]); p.y = f2bf(v[1]); p.z = f2bf(v[2]); p.w = f2bf(v[3]);
    return p;
}

// LDS-only barrier: drain this wave's LDS ops, then s_barrier.
__device__ __forceinline__ void lds_barrier() {
    asm volatile("s_waitcnt lgkmcnt(0)" ::: "memory");
    __builtin_amdgcn_s_barrier();
}

// ---------------- fused prep: f2bf(x) + transpose/convert of w_in, w_out ----------------
__device__ __forceinline__ void transpose_body(const float* __restrict__ src,
                                               ushort_t* __restrict__ dst,
                                               int K, int N, int bx, int by) {
    __shared__ float tile[32][33];
    int n0 = bx * 32, k0 = by * 32;
    int c = threadIdx.x & 31, rbase = threadIdx.x >> 5;
    #pragma unroll
    for (int i = 0; i < 4; i++) {
        int r = rbase + i * 8;
        int n = n0 + c;
        tile[r][c] = (n < N) ? src[(size_t)(k0 + r) * N + n] : 0.f;
    }
    __syncthreads();
    #pragma unroll
    for (int i = 0; i < 4; i++) {
        int r = rbase + i * 8;
        dst[(size_t)(n0 + r) * K + k0 + c] = f2bf(tile[c][r]);
    }
}

__global__ __launch_bounds__(256) void prep_kernel(const float* __restrict__ x,
                                                   const float* __restrict__ w_in,
                                                   const float* __restrict__ w_out,
                                                   ushort_t* __restrict__ xb,
                                                   ushort_t* __restrict__ bt1,
                                                   ushort_t* __restrict__ bt2) {
    int bid = blockIdx.x;
    if (bid < 2048) {                               // x -> bf16 (2M elems)
        int i = (bid * 256 + threadIdx.x) * 4;
        float4 v = *(const float4*)(x + i);
        ushort4 o;
        o.x = f2bf(v.x); o.y = f2bf(v.y); o.z = f2bf(v.z); o.w = f2bf(v.w);
        *(ushort4*)(xb + i) = o;
    } else if (bid < 2048 + 3200) {                 // w_in^T: 100 x 32 tiles
        int t = bid - 2048;
        transpose_body(w_in, bt1, HID, TOT, t % 100, t / 100);
    } else {                                        // w_out^T: 32 x 32 tiles
        int t = bid - 5248;
        transpose_body(w_out, bt2, HID, HID, t % 32, t / 32);
    }
}

// ---------------- bf16 MFMA GEMM: C[M,N] = A[M,K] @ BT[N,K]^T ----------------
// BK=64, XOR-swizzled LDS via pre-swizzled SOURCE addresses; XCD-chunked 1D grid.
// Templated epilogue: BF16OUT writes bf16 C (halves write traffic for `mixed`).
template <bool BF16OUT>
__global__ __launch_bounds__(256) void gemm_bf16(const ushort_t* __restrict__ A,
                                                 const ushort_t* __restrict__ BTm,
                                                 void* __restrict__ Cv,
                                                 int K, int Nc, int ldc, int nx) {
    __shared__ __align__(16) ushort_t As[128 * 64];   // 16KB
    __shared__ __align__(16) ushort_t Bs[128 * 64];   // 16KB
    int tid = threadIdx.x;
    int wave = tid >> 6, lane = tid & 63;
    int wr = wave >> 1, wc = wave & 1;
    int lr = lane & 15, lg = lane >> 4;

    int flat = blockIdx.x;
    int swz = (flat & 7) * ((int)gridDim.x >> 3) + (flat >> 3);   // nwg % 8 == 0
    int col0 = (swz % nx) * 128, row0 = (swz / nx) * 128;

    f32x4 acc[4][4];
    #pragma unroll
    for (int m = 0; m < 4; m++)
        #pragma unroll
        for (int n = 0; n < 4; n++) acc[m][n] = (f32x4){0.f, 0.f, 0.f, 0.f};

    int srowA = (lane >> 3);
    int skoff = ((lane & 7) ^ (lane >> 3)) * 8;

    for (int k0 = 0; k0 < K; k0 += 64) {
        #pragma unroll
        for (int j = 0; j < 4; j++) {
            int i = wave * 4 + j;
            int r = 8 * i + srowA;
            __builtin_amdgcn_global_load_lds(
                (const __attribute__((address_space(1))) void*)(A + (size_t)(row0 + r) * K + k0 + skoff),
                (__attribute__((address_space(3))) void*)(As + i * 512), 16, 0, 0);
            __builtin_amdgcn_global_load_lds(
                (const __attribute__((address_space(1))) void*)(BTm + (size_t)(col0 + r) * K + k0 + skoff),
                (__attribute__((address_space(3))) void*)(Bs + i * 512), 16, 0, 0);
        }
        __syncthreads();

        #pragma unroll
        for (int kk = 0; kk < 2; kk++) {
            short8v af[4], bf[4];
            #pragma unroll
            for (int m = 0; m < 4; m++) {
                int row = wr * 64 + m * 16 + lr;
                int pb = (row * 128 + kk * 64 + lg * 16) ^ ((row & 7) << 4);
                af[m] = *(const short8v*)((const char*)As + pb);
            }
            #pragma unroll
            for (int n = 0; n < 4; n++) {
                int row = wc * 64 + n * 16 + lr;
                int pb = (row * 128 + kk * 64 + lg * 16) ^ ((row & 7) << 4);
                bf[n] = *(const short8v*)((const char*)Bs + pb);
            }
            #pragma unroll
            for (int m = 0; m < 4; m++)
                #pragma unroll
                for (int n = 0; n < 4; n++)
                    acc[m][n] = __builtin_amdgcn_mfma_f32_16x16x32_bf16(af[m], bf[n], acc[m][n], 0, 0, 0);
        }
        __syncthreads();
    }

    #pragma unroll
    for (int m = 0; m < 4; m++) {
        #pragma unroll
        for (int n = 0; n < 4; n++) {
            int row = row0 + wr * 64 + m * 16 + lg * 4;
            int col = col0 + wc * 64 + n * 16 + lr;
            if (col < Nc) {
                if (BF16OUT) {
                    ushort_t* C = (ushort_t*)Cv;
                    #pragma unroll
                    for (int e = 0; e < 4; e++)
                        C[(size_t)(row + e) * ldc + col] = f2bf(acc[m][n][e]);
                } else {
                    float* C = (float*)Cv;
                    #pragma unroll
                    for (int e = 0; e < 4; e++)
                        C[(size_t)(row + e) * ldc + col] = acc[m][n][e];
                }
            }
        }
    }
}

// ---------------- conv + silu + split + l2norm + beta/g (bf16 mixed input) ----------------
// XCD-contiguous remap: bt = (bid&7)*256 + bid>>3.
__global__ __launch_bounds__(256) void conv_split_kernel(const ushort_t* __restrict__ mixedb,
                                                         const float* __restrict__ conv_w,
                                                         const float* __restrict__ A_log,
                                                         const float* __restrict__ dt_bias,
                                                         ushort_t* __restrict__ qb,
                                                         ushort_t* __restrict__ kb,
                                                         float* __restrict__ kn,
                                                         float* __restrict__ vn,
                                                         float* __restrict__ beta,
                                                         float* __restrict__ g) {
    int raw = blockIdx.x;
    int bt = ((raw & 7) << 8) | (raw >> 3);
    int t = bt & (TT - 1);
    int tid = threadIdx.x;
    int c0 = tid * 8;

    float val[8];
    #pragma unroll
    for (int i = 0; i < 8; i++) val[i] = 0.f;
    #pragma unroll
    for (int j = 0; j < KSZ; j++) {
        int tt = t - (KSZ - 1) + j;
        if (tt >= 0) {
            short8v v = *(const short8v*)(mixedb + (size_t)(bt - (KSZ - 1) + j) * TOT + c0);
            #pragma unroll
            for (int i = 0; i < 8; i++) val[i] += bf2f((ushort_t)v[i]) * conv_w[(c0 + i) * KSZ + j];
        }
    }
    #pragma unroll
    for (int i = 0; i < 8; i++) val[i] = siluf(val[i]);

    float ss = 0.f;
    #pragma unroll
    for (int i = 0; i < 8; i++) ss += val[i] * val[i];
    #pragma unroll
    for (int m = 1; m < 16; m <<= 1) ss += __shfl_xor(ss, m, 64);
    float rs = rsqrtf(ss + 1e-6f);

    if (tid < 128) {                      // q -> l2norm * DK^-0.5, bf16 only
        float sc = rs * 0.08838834764831845f;
        short8v pk;
        #pragma unroll
        for (int i = 0; i < 8; i++) pk[i] = (short)f2bf(val[i] * sc);
        *(short8v*)(qb + (size_t)bt * 1024 + c0) = pk;
    } else if (tid < 192) {               // k -> l2norm, f32 + bf16
        int o = c0 - 1024;
        short8v pk;
        #pragma unroll
        for (int i = 0; i < 8; i++) {
            float kv = val[i] * rs;
            kn[(size_t)bt * 512 + o + i] = kv;
            pk[i] = (short)f2bf(kv);
        }
        *(short8v*)(kb + (size_t)bt * 512 + o) = pk;
    } else {                              // v -> silu only, f32
        #pragma unroll
        for (int i = 0; i < 8; i++) vn[(size_t)bt * 512 + (c0 - 1536) + i] = val[i];
    }
    if (tid < 8) {
        beta[bt * 8 + tid] = sigmoidf_(bf2f(mixedb[(size_t)bt * TOT + 3072 + tid]));
    } else if (tid < 16) {
        int h = tid - 8;
        g[bt * 8 + h] = -expf(A_log[h]) *
                        softplusf_(bf2f(mixedb[(size_t)bt * TOT + 3080 + h]) + dt_bias[h]);
    }
}

// ---------------- Phase A: per-chunk UT transform (MFMA M, register substitution) ----------------
__global__ __launch_bounds__(256) void phaseA_kernel(const float* __restrict__ kn,
                                                     const float* __restrict__ vn,
                                                     const float* __restrict__ beta,
                                                     const float* __restrict__ g,
                                                     ushort_t* __restrict__ Wb,
                                                     ushort_t* __restrict__ Znegb,
                                                     ushort_t* __restrict__ knT,
                                                     float* __restrict__ Bvec) {
    int bh = blockIdx.x & 15, c = blockIdx.x >> 4;
    int chunk = bh * 16 + c;
    int b = bh >> 3, h = bh & 7, hk = h >> 1;
    int bt0 = b * TT + c * CHUNK;
    int tid = threadIdx.x;
    int wave = tid >> 6, lane = tid & 63;
    int lr = lane & 15, lg = lane >> 4;

    __shared__ __align__(16) ushort_t kcb[64 * 128];  // bf16 k, XOR-swizzled rows
    __shared__ float Ms[64][65];
    __shared__ float Bv[64], Bev[64], bev[64];

    if (tid < 64) {   // wave 0: cumulative log-decay scan
        float v = g[(size_t)(bt0 + tid) * 8 + h];
        #pragma unroll
        for (int off = 1; off < 64; off <<= 1) {
            float n = __shfl_up(v, off, 64);
            if (tid >= off) v += n;
        }
        Bv[tid] = v;
        Bev[tid] = expf(v);
        bev[tid] = beta[(size_t)(bt0 + tid) * 8 + h];
        Bvec[chunk * 64 + tid] = v;
    }
    // stage k as bf16, swizzled: byte (r*256 + k*2) ^ ((r&7)<<4)
    for (int i = tid; i < 1024; i += 256) {
        int r = i >> 4, k16 = i & 15;
        const float* src = kn + (size_t)(bt0 + r) * 512 + hk * 128 + k16 * 8;
        float4 v0 = *(const float4*)src;
        float4 v1 = *(const float4*)(src + 4);
        short8v pk;
        pk[0] = (short)f2bf(v0.x); pk[1] = (short)f2bf(v0.y);
        pk[2] = (short)f2bf(v0.z); pk[3] = (short)f2bf(v0.w);
        pk[4] = (short)f2bf(v1.x); pk[5] = (short)f2bf(v1.y);
        pk[6] = (short)f2bf(v1.z); pk[7] = (short)f2bf(v1.w);
        int a = (r * 256 + k16 * 16) ^ ((r & 7) << 4);
        *(short8v*)((char*)kcb + a) = pk;
    }
    __syncthreads();

    // M via MFMA: wave w -> rows [16w,16w+16), s-bands 0..w
    {
        int t_lane = wave * 16 + lr;
        short8v af[4];
        #pragma unroll
        for (int ks = 0; ks < 4; ks++) {
            int a = (t_lane * 256 + ks * 64 + lg * 16) ^ ((t_lane & 7) << 4);
            af[ks] = *(const short8v*)((const char*)kcb + a);
        }
        for (int sb = 0; sb <= wave; sb++) {
            f32x4 macc = {0.f, 0.f, 0.f, 0.f};
            int s_lane = sb * 16 + lr;
            #pragma unroll
            for (int ks = 0; ks < 4; ks++) {
                int a = (s_lane * 256 + ks * 64 + lg * 16) ^ ((s_lane & 7) << 4);
                short8v bfr = *(const short8v*)((const char*)kcb + a);
                macc = __builtin_amdgcn_mfma_f32_16x16x32_bf16(af[ks], bfr, macc, 0, 0, 0);
            }
            #pragma unroll
            for (int e = 0; e < 4; e++) {
                int trow = wave * 16 + lg * 4 + e;
                int scol = sb * 16 + lr;
                Ms[trow][scol] = (scol < trow) ? macc[e] * bev[trow] * expf(Bv[trow] - Bv[scol]) : 0.f;
            }
        }
    }

    // X init in registers: col tid<128 -> beta*v ; col tid>=128 -> beta*Gamma*k
    float Xr[64];
    if (tid < 128) {
        #pragma unroll
        for (int t = 0; t < 64; t++)
            Xr[t] = bev[t] * vn[(size_t)(bt0 + t) * 512 + hk * 128 + tid];
    } else {
        int r = tid - 128;
        #pragma unroll
        for (int t = 0; t < 64; t++)
            Xr[t] = bev[t] * Bev[t] * kn[(size_t)(bt0 + t) * 512 + hk * 128 + r];
    }
    __syncthreads();   // Ms ready

    // forward substitution, column-private, zero barriers, static indexing
    #pragma unroll
    for (int t = 1; t < 64; t++) {
        float a0 = 0.f, a1 = 0.f, a2 = 0.f, a3 = 0.f;
        #pragma unroll
        for (int s = 0; s + 4 <= t; s += 4) {
            a0 += Ms[t][s] * Xr[s];     a1 += Ms[t][s + 1] * Xr[s + 1];
            a2 += Ms[t][s + 2] * Xr[s + 2]; a3 += Ms[t][s + 3] * Xr[s + 3];
        }
        #pragma unroll
        for (int s = t & ~3; s < t; s++) a0 += Ms[t][s] * Xr[s];
        Xr[t] -= (a0 + a1) + (a2 + a3);
    }

    if (tid < 128) {
        ushort_t* Wc = Wb + (size_t)chunk * 8192 + tid;
        #pragma unroll
        for (int t = 0; t < 64; t++) Wc[t * 128] = f2bf(Xr[t]);
    } else {
        ushort_t* Zc = Znegb + (size_t)chunk * 8192 + (tid - 128);
        #pragma unroll
        for (int t = 0; t < 64; t++) Zc[t * 128] = f2bf(-Xr[t]);
    }

    // transposed bf16 k, PER-BH copy (XCD-local for phaseB)
    {
        ushort_t* kT = knT + (size_t)bh * 131072 + c * 64;
        for (int i = tid; i < 8192; i += 256) {
            int r = i >> 6, tt = i & 63;
            int a = (tt * 256 + r * 2) ^ ((tt & 7) << 4);
            kT[(size_t)r * 1024 + tt] = *(const ushort_t*)((const char*)kcb + a);
        }
    }
}

// ---------------- Phase B (MFMA, 4 waves, PINNED reg-prefetch, LDS-only barriers) ----------------
__device__ __forceinline__ int swzSt(int j, int k) {   // St[j][k] bf16
    int a = j * 256 + k * 2;
    return a ^ ((j & 7) << 4);
}
__device__ __forceinline__ int swzUt(int j, int s) {   // Ut[j][s] bf16
    int a = j * 128 + s * 2;
    return a ^ ((j & 7) << 4);
}

__global__ __launch_bounds__(256) void phaseB_mfma(const ushort_t* __restrict__ knT,
                                                   const ushort_t* __restrict__ Znegb,
                                                   const ushort_t* __restrict__ Wb,
                                                   const float* __restrict__ Bvec,
                                                   ushort_t* __restrict__ SallT,
                                                   ushort_t* __restrict__ UTg) {
    int bh = blockIdx.x & 15, cg = blockIdx.x >> 4;
    int j0 = cg * JW;
    int tid = threadIdx.x;
    int wave = tid >> 6, lane = tid & 63;
    int lr = lane & 15, lg = lane >> 4;
    int t0 = wave * 16;

    __shared__ __align__(16) ushort_t St[JW * 128];
    __shared__ __align__(16) ushort_t Ut[JW * 64];

    for (int i = tid * 8; i < JW * 128; i += 2048)
        *(int4*)(St + i) = make_int4(0, 0, 0, 0);

    f32x4 Sacc[2][2];
    #pragma unroll
    for (int fr = 0; fr < 2; fr++)
        #pragma unroll
        for (int fc = 0; fc < 2; fc++) Sacc[fr][fc] = (f32x4){0.f, 0.f, 0.f, 0.f};

    const ushort_t* kTbase = knT + (size_t)bh * 131072;
    int chunk0 = bh * 16;

    // ---- prologue: prefetch chunk 0 operands into registers (raw; convert at use)
    short8v za[4], ka[4];
    ushort_t wvr[8];
    f32x4 bvv[4];
    float b63;
    {
        const ushort_t* Zc = Znegb + (size_t)chunk0 * 8192;
        #pragma unroll
        for (int ks = 0; ks < 4; ks++)
            za[ks] = *(const short8v*)(Zc + (size_t)(t0 + lr) * 128 + ks * 32 + lg * 8);
        const ushort_t* Wc = Wb + (size_t)chunk0 * 8192 + j0;
        #pragma unroll
        for (int fc = 0; fc < 2; fc++)
            #pragma unroll
            for (int e = 0; e < 4; e++)
                wvr[fc * 4 + e] = Wc[(size_t)(t0 + lg * 4 + e) * 128 + fc * 16 + lr];
        #pragma unroll
        for (int fr = 0; fr < 2; fr++)
            #pragma unroll
            for (int ss = 0; ss < 2; ss++)
                ka[fr * 2 + ss] = *(const short8v*)(kTbase +
                    (size_t)(wave * 32 + fr * 16 + lr) * 1024 + ss * 32 + lg * 8);
        #pragma unroll
        for (int q = 0; q < 4; q++)
            bvv[q] = *(const f32x4*)(Bvec + chunk0 * 64 + (q >> 1) * 32 + lg * 8 + (q & 1) * 4);
        b63 = Bvec[chunk0 * 64 + 63];
    }

    for (int c = 0; c < NCHUNK; c++) {
        int chunk = chunk0 + c;
        // store S_c (chunk-start state) as bf16 transposed [j][r]  (global; off-path)
        ushort_t* SgT = SallT + (size_t)chunk * 16384;
        #pragma unroll
        for (int fr = 0; fr < 2; fr++)
            #pragma unroll
            for (int fc = 0; fc < 2; fc++) {
                int r0 = wave * 32 + fr * 16 + lg * 4;
                int j = j0 + fc * 16 + lr;
                *(ushort4*)(SgT + (size_t)j * 128 + r0) = pack4(Sacc[fr][fc]);
            }
        // C-input of product 1 from prefetched (raw bf16) W
        f32x4 Uacc[2];
        #pragma unroll
        for (int fc = 0; fc < 2; fc++)
            #pragma unroll
            for (int e = 0; e < 4; e++)
                Uacc[fc][e] = bf2f(wvr[fc * 4 + e]);

        lds_barrier();   // B1: St (prev chunk) visible; in-flight global ops unaffected

        // ---- product 1: U = W + (-Z) * S   (za, Uacc prefetched; St from LDS)
        #pragma unroll
        for (int ks = 0; ks < 4; ks++)
            #pragma unroll
            for (int fc = 0; fc < 2; fc++) {
                short8v sb = *(const short8v*)((const char*)St + swzSt(fc * 16 + lr, ks * 32 + lg * 8));
                Uacc[fc] = __builtin_amdgcn_mfma_f32_16x16x32_bf16(za[ks], sb, Uacc[fc], 0, 0, 0);
            }
        // write U: global bf16 transposed [j][t] + LDS transposed bf16
        ushort_t* UTc = UTg + (size_t)chunk * 8192;
        #pragma unroll
        for (int fc = 0; fc < 2; fc++) {
            int jl = fc * 16 + lr;
            ushort4 pu = pack4(Uacc[fc]);
            *(ushort4*)(UTc + (size_t)(j0 + jl) * 64 + t0 + lg * 4) = pu;
            *(ushort4*)((char*)Ut + swzUt(jl, t0 + lg * 4)) = pu;
        }
        // prefetch Z/W for chunk c+1, then PIN the issue point
        if (c + 1 < NCHUNK) {
            const ushort_t* Zn = Znegb + (size_t)(chunk + 1) * 8192;
            #pragma unroll
            for (int ks = 0; ks < 4; ks++)
                za[ks] = *(const short8v*)(Zn + (size_t)(t0 + lr) * 128 + ks * 32 + lg * 8);
            const ushort_t* Wn = Wb + (size_t)(chunk + 1) * 8192 + j0;
            #pragma unroll
            for (int fc = 0; fc < 2; fc++)
                #pragma unroll
                for (int e = 0; e < 4; e++)
                    wvr[fc * 4 + e] = Wn[(size_t)(t0 + lg * 4 + e) * 128 + fc * 16 + lr];
            __builtin_amdgcn_sched_barrier(0);
        }
        // gamma-scale state
        float gC = expf(b63);
        #pragma unroll
        for (int fr = 0; fr < 2; fr++)
            #pragma unroll
            for (int fc = 0; fc < 2; fc++)
                #pragma unroll
                for (int e = 0; e < 4; e++) Sacc[fr][fc][e] *= gC;

        lds_barrier();   // B2: Ut ready (drains Ut ds_writes + St ds_reads of product 1)

        // per-lane decay factors from prefetched Bvec
        float eb[2][8];
        #pragma unroll
        for (int ss = 0; ss < 2; ss++)
            #pragma unroll
            for (int e = 0; e < 8; e++)
                eb[ss][e] = expf(b63 - bvv[ss * 2 + (e >> 2)][e & 3]);

        // ---- product 2: S += K_hat^T * U
        #pragma unroll
        for (int fr = 0; fr < 2; fr++) {
            #pragma unroll
            for (int ss = 0; ss < 2; ss++) {
                short8v a;
                #pragma unroll
                for (int e = 0; e < 8; e++)
                    a[e] = (short)f2bf(bf2f((ushort_t)ka[fr * 2 + ss][e]) * eb[ss][e]);
                #pragma unroll
                for (int fc = 0; fc < 2; fc++) {
                    short8v ub = *(const short8v*)((const char*)Ut + swzUt(fc * 16 + lr, ss * 32 + lg * 8));
                    Sacc[fr][fc] = __builtin_amdgcn_mfma_f32_16x16x32_bf16(a, ub, Sacc[fr][fc], 0, 0, 0);
                }
            }
        }
        // prefetch kT/Bvec for chunk c+1, then PIN the issue point
        if (c + 1 < NCHUNK) {
            #pragma unroll
            for (int fr = 0; fr < 2; fr++)
                #pragma unroll
                for (int ss = 0; ss < 2; ss++)
                    ka[fr * 2 + ss] = *(const short8v*)(kTbase +
                        (size_t)(wave * 32 + fr * 16 + lr) * 1024 + (c + 1) * 64 + ss * 32 + lg * 8);
            #pragma unroll
            for (int q = 0; q < 4; q++)
                bvv[q] = *(const f32x4*)(Bvec + (chunk + 1) * 64 + (q >> 1) * 32 + lg * 8 + (q & 1) * 4);
            b63 = Bvec[(chunk + 1) * 64 + 63];
            __builtin_amdgcn_sched_barrier(0);
        }
        // write S^T bf16 for next chunk's product 1
        #pragma unroll
        for (int fr = 0; fr < 2; fr++)
            #pragma unroll
            for (int fc = 0; fc < 2; fc++) {
                int r = wave * 32 + fr * 16 + lg * 4;
                int j = fc * 16 + lr;
                *(ushort4*)((char*)St + swzSt(j, r)) = pack4(Sacc[fr][fc]);
            }
    }
}

// ---------------- Phase C (MFMA) + fused gated RMS norm + silu(z) -> bf16 ----------------
__global__ __launch_bounds__(256) void phaseC_mfma(const ushort_t* __restrict__ qb,
                                                   const ushort_t* __restrict__ kb,
                                                   const ushort_t* __restrict__ UTg,
                                                   const ushort_t* __restrict__ SallT,
                                                   const float* __restrict__ Bvec,
                                                   const ushort_t* __restrict__ mixedb,
                                                   const float* __restrict__ norm_w,
                                                   ushort_t* __restrict__ ginb) {
    int bh = blockIdx.x & 15, c = blockIdx.x >> 4;
    int chunk = bh * 16 + c;
    int b = bh >> 3, h = bh & 7, hk = h >> 1;
    int bt0 = b * TT + c * CHUNK;
    int tid = threadIdx.x, wave = tid >> 6, lane = tid & 63;
    int lr = lane & 15, lg = lane >> 4;

    __shared__ float Bv[64], Bev[64];
    __shared__ __align__(16) ushort_t Pb[64 * 64];   // P~ bf16, swizzled

    if (tid < 64) { float v = Bvec[chunk * 64 + tid]; Bv[tid] = v; Bev[tid] = expf(v); }
    __syncthreads();

    int t_lane = wave * 16 + lr;
    const ushort_t* qrow = qb + (size_t)(bt0 + t_lane) * 1024 + h * 128;
    short8v qa[4];
    #pragma unroll
    for (int ks = 0; ks < 4; ks++) qa[ks] = *(const short8v*)(qrow + ks * 32 + lg * 8);

    // ---- P = mask(exp(Bt-Bs) * Q K^T): wave w -> rows [16w,16w+16), all 4 s-bands
    #pragma unroll
    for (int sb = 0; sb < 4; sb++) {
        f32x4 pacc = {0.f, 0.f, 0.f, 0.f};
        const ushort_t* krow = kb + (size_t)(bt0 + sb * 16 + lr) * 512 + hk * 128;
        #pragma unroll
        for (int ks = 0; ks < 4; ks++) {
            short8v kf = *(const short8v*)(krow + ks * 32 + lg * 8);
            pacc = __builtin_amdgcn_mfma_f32_16x16x32_bf16(qa[ks], kf, pacc, 0, 0, 0);
        }
        int scol = sb * 16 + lr;
        #pragma unroll
        for (int e = 0; e < 4; e++) {
            int trow = wave * 16 + lg * 4 + e;
            float val = (scol <= trow) ? pacc[e] * expf(Bv[trow] - Bv[scol]) : 0.f;
            int a = (trow * 128 + scol * 2) ^ ((trow & 7) << 4);
            *(ushort_t*)((char*)Pb + a) = f2bf(val);
        }
    }

    // ---- QS: acc[n] = Q @ S (B-frags straight from global SallT), then scale by Gamma
    float Ge[4];
    #pragma unroll
    for (int e = 0; e < 4; e++) Ge[e] = Bev[wave * 16 + lg * 4 + e];
    const ushort_t* ST = SallT + (size_t)chunk * 16384;
    f32x4 acc[8];
    #pragma unroll
    for (int n = 0; n < 8; n++) {
        acc[n] = (f32x4){0.f, 0.f, 0.f, 0.f};
        int j = n * 16 + lr;
        #pragma unroll
        for (int rs = 0; rs < 4; rs++) {
            short8v sf = *(const short8v*)(ST + (size_t)j * 128 + rs * 32 + lg * 8);
            acc[n] = __builtin_amdgcn_mfma_f32_16x16x32_bf16(qa[rs], sf, acc[n], 0, 0, 0);
        }
        #pragma unroll
        for (int e = 0; e < 4; e++) acc[n][e] *= Ge[e];
    }
    __syncthreads();   // Pb ready

    // ---- acc += P~ @ U (A-frags from Pb LDS, B-frags from global UT)
    short8v pa[2];
    #pragma unroll
    for (int ks = 0; ks < 2; ks++) {
        int a = (t_lane * 128 + (ks * 32 + lg * 8) * 2) ^ ((t_lane & 7) << 4);
        pa[ks] = *(const short8v*)((const char*)Pb + a);
    }
    const ushort_t* UTc = UTg + (size_t)chunk * 8192;
    #pragma unroll
    for (int n = 0; n < 8; n++) {
        int j = n * 16 + lr;
        #pragma unroll
        for (int ks = 0; ks < 2; ks++) {
            short8v uf = *(const short8v*)(UTc + (size_t)j * 64 + ks * 32 + lg * 8);
            acc[n] = __builtin_amdgcn_mfma_f32_16x16x32_bf16(pa[ks], uf, acc[n], 0, 0, 0);
        }
    }

    // ---- fused gated RMS norm: row t = wave*16+lg*4+e owned by the 16 lr-lanes of this lg
    float rr[4];
    #pragma unroll
    for (int e = 0; e < 4; e++) {
        float s = 0.f;
        #pragma unroll
        for (int n = 0; n < 8; n++) s += acc[n][e] * acc[n][e];
        #pragma unroll
        for (int m = 1; m < 16; m <<= 1) s += __shfl_xor(s, m, 64);
        rr[e] = rsqrtf(s * (1.f / 128.f) + 1e-5f);
    }
    #pragma unroll
    for (int n = 0; n < 8; n++) {
        int j = n * 16 + lr;
        float nw = norm_w[j];
        #pragma unroll
        for (int e = 0; e < 4; e++) {
            int t = wave * 16 + lg * 4 + e;
            float z = bf2f(mixedb[(size_t)(bt0 + t) * TOT + 2048 + h * 128 + j]);
            ginb[(size_t)(bt0 + t) * 1024 + h * 128 + j] =
                f2bf(acc[n][e] * rr[e] * nw * siluf(z));
        }
    }
}

extern "C" void kernel_launch(void* const* d_in, const int* in_sizes, int n_in,
                              void* d_out, int out_size, void* d_ws, size_t ws_size,
                              hipStream_t stream) {
    const float* x       = (const float*)d_in[0];
    const float* w_in    = (const float*)d_in[1];
    const float* conv_w  = (const float*)d_in[2];
    const float* A_log   = (const float*)d_in[3];
    const float* dt_bias = (const float*)d_in[4];
    const float* norm_w  = (const float*)d_in[5];
    const float* w_out   = (const float*)d_in[6];
    float* out = (float*)d_out;

    // Workspace map (units: FLOATS; bf16 buffers take elem_count/2 floats!)
    float* ws = (float*)d_ws;
    float* mixedf = ws;                             // 3,162,112 f   mixed bf16 [2048][3088]
    float* kn    = mixedf + 3162112;                // 1,048,576 f   [2048][512] f32
    float* vn    = kn + (size_t)BT * 512;           // 1,048,576 f   [2048][512] f32
    float* beta  = vn + (size_t)BT * 512;           // 16,384 f
    float* gdec  = beta + BT * 8;                   // 16,384 f
    float* Wu    = gdec + BT * 8;                   // 1,048,576 f   Wb bf16 256*8192 us
    float* Bvec  = Wu + 1048576;                    // 16,384 f
    float* qbf   = Bvec + NBH * NCHUNK * 64;        // 1,048,576 f   qb: 2048*1024 bf16
    float* kbf   = qbf + 1048576;                   // 524,288 f     kb: 2048*512 bf16
    float* knTf  = kbf + 524288;                    // 1,048,576 f   knT: 16*131072 us (per-bh) ┐
    float* Znf   = knTf + 1048576;                  // 1,048,576 f   Zneg: 256*8192 us          ┘ bt1 spans these
    float* UTf   = Znf + 1048576;                   // 1,048,576 f   UT: 256*8192 us
    float* SallTf= UTf + 1048576;                   // 2,097,152 f   SallT: 256*16384 us; xb alias
    float* bt2f  = SallTf + 2097152;                // 524,288 f     w_out^T: 1024*1024 us
    // total: 14,221,312 f = 56.9 MB

    ushort_t* mixedb = (ushort_t*)mixedf;
    ushort_t* qb    = (ushort_t*)qbf;
    ushort_t* kb    = (ushort_t*)kbf;
    ushort_t* knTb  = (ushort_t*)knTf;
    ushort_t* Znegb = (ushort_t*)Znf;
    ushort_t* UTb   = (ushort_t*)UTf;
    ushort_t* SallT = (ushort_t*)SallTf;
    ushort_t* bt2   = (ushort_t*)bt2f;
    ushort_t* Wbb   = (ushort_t*)Wu;
    // liveness-disjoint aliases:
    ushort_t* xb    = (ushort_t*)SallTf;            // x bf16: dead before phaseB writes SallT
    ushort_t* bt1   = (ushort_t*)knTf;              // w_in^T bf16: fits in knTf+Znf; dead before phaseA
    ushort_t* ginb  = (ushort_t*)qbf;               // GEMM2 input: qb dead after phaseC reads it

    // 0) fused converts (f2bf + both weight transposes)
    prep_kernel<<<6272, 256, 0, stream>>>(x, w_in, w_out, xb, bt1, bt2);

    // 1) mixed(bf16) = x @ w_in  (BK=64, XCD-chunked; grid 25x16 = 400)
    gemm_bf16<true><<<400, 256, 0, stream>>>(xb, bt1, mixedb, HID, TOT, TOT, NPAD1 / 128);

    // 2) conv + silu + split + l2norm + beta/g (bf16 mixed, XCD-contiguous t remap)
    conv_split_kernel<<<BT, 256, 0, stream>>>(mixedb, conv_w, A_log, dt_bias, qb, kb, kn, vn, beta, gdec);

    // 3) chunkwise delta-rule scan (bh = bid&15 -> per-bh XCD affinity)
    phaseA_kernel<<<NBH * NCHUNK, 256, 0, stream>>>(kn, vn, beta, gdec, Wbb, Znegb, knTb, Bvec);
    phaseB_mfma<<<NBH * 4, 256, 0, stream>>>(knTb, Znegb, Wbb, Bvec, SallT, UTb);
    // 4) phaseC + fused gated RMS norm + silu(z) -> bf16 gin
    phaseC_mfma<<<NBH * NCHUNK, 256, 0, stream>>>(qb, kb, UTb, SallT, Bvec, mixedb, norm_w, ginb);

    // 5) out = gin @ w_out  (fp32 out, BK=64, XCD-chunked; grid 8x16 = 128)
    gemm_bf16<false><<<128, 256, 0, stream>>>(ginb, bt2, out, HID, HID, HID, HID / 128);
}